// Round 6
// baseline (559.120 us; speedup 1.0000x reference)
//
#include <hip/hip_runtime.h>
#include <math.h>

#define HID 32
#define HOR 12
#define NB  256    // first-level blocks; k_binscan's 256 threads own one block each
#define GSH 6      // group shift: 64 nodes per group
#define GW  64     // group width
#define NPT 4      // nodes per thread in k_gates
#define TILE 4096  // edges per scatter tile
#define TPB  256   // scatter threads per block
#define U    16    // TILE / TPB
#define BINS 1024  // padded bin count (ng <= 1024 required)

__device__ __forceinline__ float sigmoidf_(float x) { return 1.0f / (1.0f + expf(-x)); }

// ---------------------------------------------------------------------------
// Bucket sort by node id at 64-node granularity (node < 65536 required).
// k_hist: per-block 782-bin histograms of src>>6 and dst>>6 (LDS atomics).
// k_binscan/k_binbase: per-(block,bin) global offsets + group bases.
// k_scatter: TILE-SORTED staged scatter — each tile is sorted into LDS by
//   group, then flushed in coalesced full-line runs (kills the 3.3x
//   partial-line write amplification the naive per-edge scatter showed).
// k_degsum: per src-group LDS weighted histogram -> dinv.
// k_gather: DIRECT from group-sorted tmpD into an 8KB LDS accumulator
//   acc[64 nodes][32 feats] (bank = feat -> <=2-way conflict = free),
//   no second-level sort, no epair round trip.
// ---------------------------------------------------------------------------

__global__ __launch_bounds__(1024) void k_hist(const int* __restrict__ src,
                                               const int* __restrict__ dst,
                                               int* __restrict__ hist,
                                               int E, int chunk, int ng) {
    __shared__ int hS[BINS], hD[BINS];
    int t = threadIdx.x, b = blockIdx.x;
    for (int i = t; i < ng; i += 1024) { hS[i] = 0; hD[i] = 0; }
    __syncthreads();
    int beg = b * chunk, end = min(E, beg + chunk);
    for (int e = beg + t; e < end; e += 1024) {
        atomicAdd(&hS[src[e] >> GSH], 1);
        atomicAdd(&hD[dst[e] >> GSH], 1);
    }
    __syncthreads();
    for (int i = t; i < ng; i += 1024) {
        hist[(size_t)i * NB + b] = hS[i];               // S bins: [0, ng)
        hist[((size_t)ng + i) * NB + b] = hD[i];        // D bins: [ng, 2ng)
    }
}

// per-bin exclusive scan across the NB blocks (one block per bin)
__global__ __launch_bounds__(256) void k_binscan(const int* __restrict__ hist,
                                                 int* __restrict__ off,
                                                 int* __restrict__ binTot, int ng2) {
    __shared__ int s[256];
    int b2 = blockIdx.x, t = threadIdx.x;
    int v = hist[(size_t)b2 * NB + t];                  // coalesced
    s[t] = v;
    __syncthreads();
    for (int o = 1; o < 256; o <<= 1) {
        int x = (t >= o) ? s[t - o] : 0;
        __syncthreads();
        s[t] += x;
        __syncthreads();
    }
    off[(size_t)t * ng2 + b2] = s[t] - v;               // block-major (scattered)
    if (t == 255) binTot[b2] = s[255];
}

// 2 blocks x 1024: block 0 scans S bin totals, block 1 scans D bin totals.
__global__ __launch_bounds__(1024) void k_binbase(const int* __restrict__ binTot,
                                                  int* __restrict__ baseS, int* __restrict__ baseD,
                                                  int E, int ng) {
    __shared__ int buf[1024];
    int t = threadIdx.x;
    int isD = blockIdx.x;
    int sum = (t < ng) ? binTot[isD * ng + t] : 0;
    buf[t] = sum;
    __syncthreads();
    for (int o = 1; o < 1024; o <<= 1) {
        int v = (t >= o) ? buf[t - o] : 0;
        __syncthreads();
        buf[t] += v;
        __syncthreads();
    }
    int base = buf[t] - sum;                            // exclusive
    int* B = isD ? baseD : baseS;
    if (t < ng) B[t] = base;
    if (t == 0) B[ng] = E;
}

// tile-sorted staged scatter: pass 0 = S keying -> tmpS, pass 1 = D keying -> tmpD
__global__ __launch_bounds__(256) void k_scatter(const int* __restrict__ src,
                                                 const int* __restrict__ dst,
                                                 const float* __restrict__ w,
                                                 const int* __restrict__ off,
                                                 const int* __restrict__ baseS,
                                                 const int* __restrict__ baseD,
                                                 int2* __restrict__ tmpS, int2* __restrict__ tmpD,
                                                 int E, int chunk, int ng) {
    __shared__ int2 stage[TILE];                 // 32 KB
    __shared__ unsigned short stageG[TILE];      // 8 KB
    __shared__ int cnt[BINS];                    // counts -> tile-local excl offsets
    __shared__ int gcur[BINS];                   // running global cursor per bin
    __shared__ int aux[TPB];
    int t = threadIdx.x, b = blockIdx.x;
    int beg = b * chunk, end = min(E, beg + chunk);
    int ng2 = 2 * ng;

    for (int pass = 0; pass < 2; ++pass) {
        for (int i = t; i < ng; i += TPB)
            gcur[i] = (pass == 0) ? off[(size_t)b * ng2 + i] + baseS[i]
                                  : off[(size_t)b * ng2 + ng + i] + baseD[i];
        __syncthreads();

        for (int tb = beg; tb < end; tb += TILE) {
            int tcount = min(TILE, end - tb);
            for (int i = t; i < BINS; i += TPB) cnt[i] = 0;
            __syncthreads();

            // load + rank (full unroll -> static register indices)
            int g_[U], r_[U];
            int2 p_[U];
            #pragma unroll
            for (int u = 0; u < U; ++u) {
                int li = u * TPB + t;
                g_[u] = -1;
                if (li < tcount) {
                    int e = tb + li;
                    int s = src[e];
                    int wb = __float_as_int(w[e]);
                    int g; int2 p;
                    if (pass == 0) { g = s >> GSH; p = make_int2(s, wb); }
                    else { int d = dst[e]; g = d >> GSH; p = make_int2(s | ((d & (GW - 1)) << 16), wb); }
                    g_[u] = g; p_[u] = p;
                    r_[u] = atomicAdd(&cnt[g], 1);
                }
            }
            __syncthreads();

            // exclusive scan of cnt over BINS bins (thread owns 4 contiguous)
            int c0 = cnt[4 * t], c1 = cnt[4 * t + 1], c2 = cnt[4 * t + 2], c3 = cnt[4 * t + 3];
            int q1 = c0, q2 = c0 + c1, q3 = c0 + c1 + c2, tsum = q3 + c3;
            aux[t] = tsum;
            __syncthreads();
            for (int o = 1; o < TPB; o <<= 1) {
                int v = (t >= o) ? aux[t - o] : 0;
                __syncthreads();
                aux[t] += v;
                __syncthreads();
            }
            int excl = aux[t] - tsum;
            cnt[4 * t] = excl; cnt[4 * t + 1] = excl + q1;
            cnt[4 * t + 2] = excl + q2; cnt[4 * t + 3] = excl + q3;
            __syncthreads();

            // place into staging (tile now sorted by group)
            #pragma unroll
            for (int u = 0; u < U; ++u) {
                if (g_[u] >= 0) {
                    int pos = cnt[g_[u]] + r_[u];
                    stage[pos] = p_[u];
                    stageG[pos] = (unsigned short)g_[u];
                }
            }
            __syncthreads();

            // coalesced flush: consecutive i in the same group -> consecutive addrs
            int2* out = (pass == 0) ? tmpS : tmpD;
            for (int i = t; i < tcount; i += TPB) {
                int g = stageG[i];
                out[gcur[g] + (i - cnt[g])] = stage[i];
            }
            __syncthreads();

            gcur[4 * t] += c0; gcur[4 * t + 1] += c1;
            gcur[4 * t + 2] += c2; gcur[4 * t + 3] += c3;
            __syncthreads();
        }
        __syncthreads();
    }
}

// per src-group: LDS float histogram over low 6 bits -> dinv (no global atomics)
__global__ __launch_bounds__(256) void k_degsum(const int2* __restrict__ tmpS,
                                                const int* __restrict__ baseS,
                                                float* __restrict__ dinv, int N) {
    __shared__ float h[GW];
    int g = blockIdx.x, t = threadIdx.x;
    if (t < GW) h[t] = 0.0f;
    __syncthreads();
    int beg = baseS[g], end = baseS[g + 1];
    for (int i = beg + t; i < end; i += 256) {
        int2 p = tmpS[i];
        atomicAdd(&h[p.x & (GW - 1)], __int_as_float(p.y));
    }
    __syncthreads();
    int n = (g << GSH) + t;
    if (t < GW && n < N) { float s = h[t]; dinv[n] = (s > 0.0f) ? rsqrtf(s) : 0.0f; }
}

// flag bit0 = any h0 nonzero, bit1 = any c0 nonzero
__global__ void k_flags(const float* __restrict__ h0, const float* __restrict__ c0,
                        int* __restrict__ flag, int total) {
    int i = blockIdx.x * 256 + threadIdx.x;
    float a = (i < total) ? h0[i] : 0.0f;
    float c = (i < total) ? c0[i] : 0.0f;
    unsigned long long ba = __ballot(a != 0.0f);
    unsigned long long bc = __ballot(c != 0.0f);
    if ((threadIdx.x & 63) == 0) {
        int m = (ba ? 1 : 0) | (bc ? 2 : 0);
        if (m) atomicOr(flag, m);
    }
}

// direct gather: per dst-group block, accumulate into LDS acc[64][32].
// bank(acc[dlow][f]) = f -> at most 2 lanes/bank per wave access (free).
__global__ __launch_bounds__(256) void k_gather(const int2* __restrict__ tmpD,
                                                const int* __restrict__ baseD,
                                                const float* __restrict__ dinv,
                                                const float* __restrict__ X,
                                                const float* __restrict__ H0,
                                                const int* __restrict__ hflag,
                                                float* __restrict__ LX, float* __restrict__ LH,
                                                int N) {
    __shared__ float accX[GW][HID];   // 8 KB
    __shared__ float accH[GW][HID];   // 8 KB
    int g = blockIdx.x, t = threadIdx.x;
    int f = t & 31, sub = t >> 5;     // 8 edges in flight
    int fl = *hflag;
    for (int i = t; i < GW * HID; i += 256) {
        ((float*)accX)[i] = 0.0f;
        ((float*)accH)[i] = 0.0f;
    }
    __syncthreads();
    int beg = baseD[g], end = baseD[g + 1];
    if (fl & 1) {
        for (int i = beg + sub; i < end; i += 8) {
            int2 p = tmpD[i];
            int s = p.x & 0xFFFF;
            int dlow = (p.x >> 16) & (GW - 1);
            float nw = -dinv[s] * __int_as_float(p.y) * dinv[(g << GSH) + dlow];
            atomicAdd(&accX[dlow][f], nw * X[(s << 5) + f]);
            atomicAdd(&accH[dlow][f], nw * H0[(s << 5) + f]);
        }
    } else {
        for (int i = beg + sub; i < end; i += 8) {
            int2 p = tmpD[i];
            int s = p.x & 0xFFFF;
            int dlow = (p.x >> 16) & (GW - 1);
            float nw = -dinv[s] * __int_as_float(p.y) * dinv[(g << GSH) + dlow];
            atomicAdd(&accX[dlow][f], nw * X[(s << 5) + f]);
        }
    }
    __syncthreads();
    for (int i = t; i < GW * HID; i += 256) {
        int n = (g << GSH) + (i >> 5);
        if (n < N) {
            LX[(n << 5) + (i & 31)] = ((float*)accX)[i];
            if (fl & 1) LH[(n << 5) + (i & 31)] = ((float*)accH)[i];
        }
    }
}

// Per (node-group g of NPT nodes, out-feature j): fused LSTM cell.
// Fast path (h0==0 && c0==0, detected at runtime): F-gate dead (C = I*T),
// h/lh terms are exact zero-adds -> 3 gates x 2 input types. Bit-identical.
__global__ __launch_bounds__(256) void k_gates(
    const float* __restrict__ X, const float* __restrict__ LX,
    const float* __restrict__ H0, const float* __restrict__ LH,
    const float* __restrict__ C0,
    const float* __restrict__ Wx, const float* __restrict__ bx,
    const float* __restrict__ Wh, const float* __restrict__ bh,
    const float* __restrict__ wc, const float* __restrict__ b,
    const int* __restrict__ flag,
    float* __restrict__ outH, float* __restrict__ outC, int N) {
    int tid = blockIdx.x * 256 + threadIdx.x;
    int g = tid >> 5;           // node group
    int j = tid & 31;           // output feature
    int n0 = g * NPT;
    if (n0 >= N) return;
    int cnt = min(NPT, N - n0);
    int f2 = *flag;

    if (f2 == 0) {
        // ---- fast path: h0 == 0 and c0 == 0 ----
        float xk[NPT], lxk[NPT];
        #pragma unroll
        for (int i = 0; i < NPT; ++i) { xk[i] = 0.0f; lxk[i] = 0.0f; }
        for (int i = 0; i < cnt; ++i) {
            int base = (n0 + i) << 5;
            xk[i]  = X[base + j];
            lxk[i] = LX[base + j];
        }
        float p0[NPT], p2[NPT], p3[NPT];
        float b0 = bx[0 * HID + j] + bh[0 * HID + j] + b[0 * HID + j];
        float b2 = bx[2 * HID + j] + bh[2 * HID + j] + b[2 * HID + j];
        float b3 = bx[3 * HID + j] + bh[3 * HID + j] + b[3 * HID + j];
        #pragma unroll
        for (int i = 0; i < NPT; ++i) { p0[i] = b0; p2[i] = b2; p3[i] = b3; }

        #pragma unroll 4
        for (int k = 0; k < HID; ++k) {
            int row = k * HID + j;
            float w00 = Wx[0 * 2048 + row], w01 = Wx[0 * 2048 + 1024 + row];
            float w20 = Wx[2 * 2048 + row], w21 = Wx[2 * 2048 + 1024 + row];
            float w30 = Wx[3 * 2048 + row], w31 = Wx[3 * 2048 + 1024 + row];
            #pragma unroll
            for (int i = 0; i < NPT; ++i) {
                float xv  = __shfl(xk[i],  k, 32);
                float lxv = __shfl(lxk[i], k, 32);
                p0[i] += xv * w00 + lxv * w01;
                p2[i] += xv * w20 + lxv * w21;
                p3[i] += xv * w30 + lxv * w31;
            }
        }

        float wc2 = wc[2 * HID + j];
        for (int i = 0; i < cnt; ++i) {
            int base = (n0 + i) << 5;
            float I = sigmoidf_(p0[i]);
            float T = tanhf(p2[i]);
            float C = I * T;
            float O = sigmoidf_(p3[i] + wc2 * C);
            outH[base + j] = O * tanhf(C);
            outC[base + j] = C;
        }
        return;
    }

    // ---- general path ----
    float xk[NPT], lxk[NPT], hk[NPT], lhk[NPT];
    #pragma unroll
    for (int i = 0; i < NPT; ++i) { xk[i] = 0.0f; lxk[i] = 0.0f; hk[i] = 0.0f; lhk[i] = 0.0f; }
    for (int i = 0; i < cnt; ++i) {
        int base = (n0 + i) << 5;
        xk[i]  = X[base + j];
        lxk[i] = LX[base + j];
        hk[i]  = H0[base + j];
        lhk[i] = (f2 & 1) ? LH[base + j] : 0.0f;   // LH only valid if h0 nonzero
    }

    float pre[4][NPT];
    #pragma unroll
    for (int gt = 0; gt < 4; ++gt) {
        float bb = bx[gt * HID + j] + bh[gt * HID + j] + b[gt * HID + j];
        #pragma unroll
        for (int i = 0; i < NPT; ++i) pre[gt][i] = bb;
    }

    #pragma unroll 2
    for (int k = 0; k < HID; ++k) {
        float w0[4], w1[4], w2[4], w3[4];
        int row = k * HID + j;
        #pragma unroll
        for (int gt = 0; gt < 4; ++gt) {
            w0[gt] = Wx[gt * 2048 + row];
            w1[gt] = Wx[gt * 2048 + 1024 + row];
            w2[gt] = Wh[gt * 2048 + row];
            w3[gt] = Wh[gt * 2048 + 1024 + row];
        }
        #pragma unroll
        for (int i = 0; i < NPT; ++i) {
            float xv  = __shfl(xk[i],  k, 32);
            float lxv = __shfl(lxk[i], k, 32);
            float hv  = __shfl(hk[i],  k, 32);
            float lhv = __shfl(lhk[i], k, 32);
            #pragma unroll
            for (int gt = 0; gt < 4; ++gt)
                pre[gt][i] += xv * w0[gt] + lxv * w1[gt] + hv * w2[gt] + lhv * w3[gt];
        }
    }

    float wc0 = wc[0 * HID + j], wc1 = wc[1 * HID + j], wc2 = wc[2 * HID + j];
    for (int i = 0; i < cnt; ++i) {
        int base = (n0 + i) << 5;
        float c0v = C0[base + j];
        float I  = sigmoidf_(pre[0][i] + wc0 * c0v);
        float Fg = sigmoidf_(pre[1][i] + wc1 * c0v);
        float T  = tanhf(pre[2][i]);
        float C  = Fg * c0v + I * T;
        float O  = sigmoidf_(pre[3][i] + wc2 * C);
        float H  = O * tanhf(C);
        outH[base + j] = H;
        outC[base + j] = C;
    }
}

// h[n,t] = b_lin[t] + sum_k relu(H[n,k]) * W_lin[k,t]
__global__ void k_head(const float* __restrict__ H, const float* __restrict__ Wl,
                       const float* __restrict__ bl, float* __restrict__ hout, int N) {
    int tid = blockIdx.x * 256 + threadIdx.x;
    int n = tid / HOR;
    int t = tid - n * HOR;
    if (n >= N) return;
    float acc = bl[t];
    #pragma unroll
    for (int k = 0; k < HID; ++k) {
        float v = H[(n << 5) + k];
        acc += fmaxf(v, 0.0f) * Wl[k * HOR + t];
    }
    hout[n * HOR + t] = acc;
}

extern "C" void kernel_launch(void* const* d_in, const int* in_sizes, int n_in,
                              void* d_out, int out_size, void* d_ws, size_t ws_size,
                              hipStream_t stream) {
    const float* x  = (const float*)d_in[0];
    const int*   ei = (const int*)d_in[1];
    const float* ew = (const float*)d_in[2];
    const float* Wx = (const float*)d_in[3];
    const float* bx = (const float*)d_in[4];
    const float* Wh = (const float*)d_in[5];
    const float* bh = (const float*)d_in[6];
    const float* wc = (const float*)d_in[7];
    const float* b  = (const float*)d_in[8];
    const float* Wl = (const float*)d_in[9];
    const float* bl = (const float*)d_in[10];
    const float* h0 = (const float*)d_in[11];
    const float* c0 = (const float*)d_in[12];

    int N = in_sizes[0] / HID;      // x is (N,1,32)
    int E = in_sizes[2];            // edge_weight is (E,)
    const int* src = ei;
    const int* dst = ei + E;

    int ng = (N + GW - 1) >> GSH;   // 782 groups (requires N <= 65536)
    int ng2 = 2 * ng;
    int chunk = (E + NB - 1) / NB;  // edges per hist/scatter block

    // workspace (4-byte units):
    // [tmpD 2E] [tmpS 2E] [LX N*32] [LH N*32]
    // [hist ng2*NB] [off ng2*NB] [binTot 2048] [baseS ng+1] [baseD ng+1] [dinv N] [flag 1]
    int* wsi = (int*)d_ws;
    int2*  tmpD   = (int2*)wsi;
    int2*  tmpS   = (int2*)(wsi + 2 * (size_t)E);
    float* LX     = (float*)(wsi + 4 * (size_t)E);
    float* LH     = LX + (size_t)N * HID;
    int*   hist   = (int*)(LH + (size_t)N * HID);
    int*   off    = hist + (size_t)ng2 * NB;
    int*   binTot = off + (size_t)ng2 * NB;
    int*   baseS  = binTot + 2048;
    int*   baseD  = baseS + (ng + 1);
    float* dinv   = (float*)(baseD + (ng + 1));
    int*   flag   = (int*)(dinv + N);

    float* hOut = (float*)d_out;            // (N,12)
    float* HOut = hOut + (size_t)N * HOR;   // (N,32)
    float* COut = HOut + (size_t)N * HID;   // (N,32)

    hipMemsetAsync(flag, 0, sizeof(int), stream);

    k_hist<<<NB, 1024, 0, stream>>>(src, dst, hist, E, chunk, ng);
    k_binscan<<<ng2, 256, 0, stream>>>(hist, off, binTot, ng2);
    k_binbase<<<2, 1024, 0, stream>>>(binTot, baseS, baseD, E, ng);
    k_scatter<<<NB, TPB, 0, stream>>>(src, dst, ew, off, baseS, baseD, tmpS, tmpD, E, chunk, ng);
    k_degsum<<<ng, 256, 0, stream>>>(tmpS, baseS, dinv, N);
    k_flags<<<(N * HID + 255) / 256, 256, 0, stream>>>(h0, c0, flag, N * HID);

    k_gather<<<ng, 256, 0, stream>>>(tmpD, baseD, dinv, x, h0, flag, LX, LH, N);

    int gThreads = ((N + NPT - 1) / NPT) * 32;
    k_gates<<<(gThreads + 255) / 256, 256, 0, stream>>>(x, LX, h0, LH, c0,
                                                        Wx, bx, Wh, bh, wc, b, flag,
                                                        HOut, COut, N);

    k_head<<<(N * HOR + 255) / 256, 256, 0, stream>>>(HOut, Wl, bl, hOut, N);
}

// Round 7
// 323.907 us; speedup vs baseline: 1.7262x; 1.7262x over previous
//
#include <hip/hip_runtime.h>
#include <math.h>

#define HID 32
#define HOR 12
#define NB  256   // first-level blocks; k_binscan's 256 threads own one block each
#define GSH 6     // group shift: 64 nodes per group
#define GW  64    // group width
#define NPT 4     // nodes per thread in k_fused

__device__ __forceinline__ float sigmoidf_(float x) { return 1.0f / (1.0f + expf(-x)); }

// ---------------------------------------------------------------------------
// Bucket sort by node id at 64-node granularity (node < 65536 required).
// Identical to the proven round-5 pipeline. The only structural change this
// round: k_gather + k_gates + k_head are fused into k_fused (same thread
// mapping, LX/LH/H round-trips eliminated, accumulators stay in registers).
// ---------------------------------------------------------------------------

__global__ __launch_bounds__(1024) void k_hist(const int* __restrict__ src,
                                               const int* __restrict__ dst,
                                               int* __restrict__ hist,
                                               int E, int chunk, int ng) {
    __shared__ int hS[1024], hD[1024];
    int t = threadIdx.x, b = blockIdx.x;
    for (int i = t; i < ng; i += 1024) { hS[i] = 0; hD[i] = 0; }
    __syncthreads();
    int beg = b * chunk, end = min(E, beg + chunk);
    for (int e = beg + t; e < end; e += 1024) {
        atomicAdd(&hS[src[e] >> GSH], 1);
        atomicAdd(&hD[dst[e] >> GSH], 1);
    }
    __syncthreads();
    for (int i = t; i < ng; i += 1024) {
        hist[(size_t)i * NB + b] = hS[i];               // S bins: [0, ng)
        hist[((size_t)ng + i) * NB + b] = hD[i];        // D bins: [ng, 2ng)
    }
}

// per-bin exclusive scan across the NB blocks (one block per bin)
__global__ __launch_bounds__(256) void k_binscan(const int* __restrict__ hist,
                                                 int* __restrict__ off,
                                                 int* __restrict__ binTot, int ng2) {
    __shared__ int s[256];
    int b2 = blockIdx.x, t = threadIdx.x;
    int v = hist[(size_t)b2 * NB + t];                  // coalesced
    s[t] = v;
    __syncthreads();
    for (int o = 1; o < 256; o <<= 1) {
        int x = (t >= o) ? s[t - o] : 0;
        __syncthreads();
        s[t] += x;
        __syncthreads();
    }
    off[(size_t)t * ng2 + b2] = s[t] - v;               // block-major (scattered)
    if (t == 255) binTot[b2] = s[255];
}

// 2 blocks x 1024: block 0 scans S bin totals, block 1 scans D bin totals.
__global__ __launch_bounds__(1024) void k_binbase(const int* __restrict__ binTot,
                                                  int* __restrict__ baseS, int* __restrict__ baseD,
                                                  int* __restrict__ rowptr,
                                                  int E, int ng, int N) {
    __shared__ int buf[1024];
    int t = threadIdx.x;
    int isD = blockIdx.x;
    int sum = (t < ng) ? binTot[isD * ng + t] : 0;
    buf[t] = sum;
    __syncthreads();
    for (int o = 1; o < 1024; o <<= 1) {
        int v = (t >= o) ? buf[t - o] : 0;
        __syncthreads();
        buf[t] += v;
        __syncthreads();
    }
    int base = buf[t] - sum;                            // exclusive
    int* B = isD ? baseD : baseS;
    if (t < ng) B[t] = base;
    if (t == 0) { B[ng] = E; if (!isD) rowptr[N] = E; }
}

// per-edge scatter into 64-wide groups (both keyings) using LDS cursors.
__global__ __launch_bounds__(1024) void k_scatter(const int* __restrict__ src,
                                                  const int* __restrict__ dst,
                                                  const float* __restrict__ w,
                                                  const int* __restrict__ off,
                                                  const int* __restrict__ baseS,
                                                  const int* __restrict__ baseD,
                                                  int2* __restrict__ tmpS, int2* __restrict__ tmpD,
                                                  int E, int chunk, int ng) {
    __shared__ int cS[1024], cD[1024];
    int t = threadIdx.x, b = blockIdx.x;
    int ng2 = 2 * ng;
    for (int i = t; i < ng; i += 1024) {
        cS[i] = off[(size_t)b * ng2 + i] + baseS[i];          // coalesced
        cD[i] = off[(size_t)b * ng2 + ng + i] + baseD[i];
    }
    __syncthreads();
    int beg = b * chunk, end = min(E, beg + chunk);
    for (int e = beg + t; e < end; e += 1024) {
        int s = src[e], d = dst[e];
        int wb = __float_as_int(w[e]);
        int pS = atomicAdd(&cS[s >> GSH], 1);
        tmpS[pS] = make_int2(s, wb);
        int pD = atomicAdd(&cD[d >> GSH], 1);
        tmpD[pD] = make_int2(s | ((d & (GW - 1)) << 16), wb); // src fits 16 bits
    }
}

// per src-group: LDS float histogram over low 6 bits -> dinv (no global atomics)
__global__ __launch_bounds__(256) void k_degsum(const int2* __restrict__ tmpS,
                                                const int* __restrict__ baseS,
                                                float* __restrict__ dinv, int N) {
    __shared__ float h[GW];
    int g = blockIdx.x, t = threadIdx.x;
    if (t < GW) h[t] = 0.0f;
    __syncthreads();
    int beg = baseS[g], end = baseS[g + 1];
    for (int i = beg + t; i < end; i += 256) {
        int2 p = tmpS[i];
        atomicAdd(&h[p.x & (GW - 1)], __int_as_float(p.y));
    }
    __syncthreads();
    int n = (g << GSH) + t;
    if (t < GW && n < N) { float s = h[t]; dinv[n] = (s > 0.0f) ? rsqrtf(s) : 0.0f; }
}

// per dst-group: low-bits count + scan -> rowptr; then bin edges to exact dst,
// computing nw now that dinv exists. Within-dst order is arbitrary (sum).
__global__ __launch_bounds__(256) void k_scatter2(const int2* __restrict__ tmpD,
                                                  const int* __restrict__ baseD,
                                                  const float* __restrict__ dinv,
                                                  int* __restrict__ rowptr,
                                                  int2* __restrict__ epair, int N) {
    __shared__ int h[GW], cur[GW];
    int g = blockIdx.x, t = threadIdx.x;
    if (t < GW) h[t] = 0;
    __syncthreads();
    int beg = baseD[g], end = baseD[g + 1];
    for (int i = beg + t; i < end; i += 256) atomicAdd(&h[(tmpD[i].x >> 16) & (GW - 1)], 1);
    __syncthreads();
    int v = (t < GW) ? h[t] : 0;
    for (int o = 1; o < GW; o <<= 1) {
        int x = (t < GW && t >= o) ? h[t - o] : 0;
        __syncthreads();
        if (t < GW && t >= o) h[t] += x;
        __syncthreads();
    }
    if (t < GW) {
        int excl = h[t] - v;
        int n = (g << GSH) + t;
        if (n < N) rowptr[n] = beg + excl;
        cur[t] = beg + excl;
    }
    __syncthreads();
    for (int i = beg + t; i < end; i += 256) {
        int2 p = tmpD[i];
        int low = (p.x >> 16) & (GW - 1);
        int s = p.x & 0xFFFF;
        int pos = atomicAdd(&cur[low], 1);
        float nw = -dinv[s] * __int_as_float(p.y) * dinv[(g << GSH) + low];
        epair[pos] = make_int2(s, __float_as_int(nw));
    }
}

// flag bit0 = any h0 nonzero, bit1 = any c0 nonzero
__global__ void k_flags(const float* __restrict__ h0, const float* __restrict__ c0,
                        int* __restrict__ flag, int total) {
    int i = blockIdx.x * 256 + threadIdx.x;
    float a = (i < total) ? h0[i] : 0.0f;
    float c = (i < total) ? c0[i] : 0.0f;
    unsigned long long ba = __ballot(a != 0.0f);
    unsigned long long bc = __ballot(c != 0.0f);
    if ((threadIdx.x & 63) == 0) {
        int m = (ba ? 1 : 0) | (bc ? 2 : 0);
        if (m) atomicOr(flag, m);
    }
}

// -------- fused gather + gates + head --------
// Per (node-group g of NPT nodes, lane j = out-feature): gather LX (and LH)
// into registers from epair, run the LSTM cell, write HOut/COut, and compute
// the HOR-wide head inline. No LX/LH/H round trips through memory.
__global__ __launch_bounds__(256) void k_fused(
    const int* __restrict__ rowptr, const int2* __restrict__ epair,
    const float* __restrict__ X, const float* __restrict__ H0,
    const float* __restrict__ C0,
    const float* __restrict__ Wx, const float* __restrict__ bx,
    const float* __restrict__ Wh, const float* __restrict__ bh,
    const float* __restrict__ wc, const float* __restrict__ b,
    const float* __restrict__ Wl, const float* __restrict__ bl,
    const int* __restrict__ flag,
    float* __restrict__ hOut, float* __restrict__ outH, float* __restrict__ outC,
    int N) {
    int tid = blockIdx.x * 256 + threadIdx.x;
    int g = tid >> 5;           // node group
    int j = tid & 31;           // output feature
    int n0 = g * NPT;
    if (n0 >= N) return;
    int cnt = min(NPT, N - n0);
    int f2 = *flag;
    float blv = (j < HOR) ? bl[j] : 0.0f;

    if (f2 == 0) {
        // ---- fast path: h0 == 0 and c0 == 0 ----
        float xk[NPT], lxk[NPT];
        #pragma unroll
        for (int i = 0; i < NPT; ++i) { xk[i] = 0.0f; lxk[i] = 0.0f; }
        for (int i = 0; i < cnt; ++i) {
            int n = n0 + i;
            xk[i] = X[(n << 5) + j];
            int beg = rowptr[n], end = rowptr[n + 1];
            float a = 0.0f;
            #pragma unroll 4
            for (int e = beg; e < end; ++e) {
                int2 p = epair[e];
                a += __int_as_float(p.y) * X[(p.x << 5) + j];
            }
            lxk[i] = a;
        }

        // gates: 0=I, 2=T, 3=O  (gate 1 = F is dead since c0 == 0)
        float p0[NPT], p2[NPT], p3[NPT];
        float b0 = bx[0 * HID + j] + bh[0 * HID + j] + b[0 * HID + j];
        float b2 = bx[2 * HID + j] + bh[2 * HID + j] + b[2 * HID + j];
        float b3 = bx[3 * HID + j] + bh[3 * HID + j] + b[3 * HID + j];
        #pragma unroll
        for (int i = 0; i < NPT; ++i) { p0[i] = b0; p2[i] = b2; p3[i] = b3; }

        #pragma unroll 4
        for (int k = 0; k < HID; ++k) {
            int row = k * HID + j;
            float w00 = Wx[0 * 2048 + row], w01 = Wx[0 * 2048 + 1024 + row];
            float w20 = Wx[2 * 2048 + row], w21 = Wx[2 * 2048 + 1024 + row];
            float w30 = Wx[3 * 2048 + row], w31 = Wx[3 * 2048 + 1024 + row];
            #pragma unroll
            for (int i = 0; i < NPT; ++i) {
                float xv  = __shfl(xk[i],  k, 32);
                float lxv = __shfl(lxk[i], k, 32);
                p0[i] += xv * w00 + lxv * w01;
                p2[i] += xv * w20 + lxv * w21;
                p3[i] += xv * w30 + lxv * w31;
            }
        }

        float wc2 = wc[2 * HID + j];
        for (int i = 0; i < cnt; ++i) {
            int n = n0 + i;
            int base = n << 5;
            float I = sigmoidf_(p0[i]);
            float T = tanhf(p2[i]);
            float C = I * T;
            float O = sigmoidf_(p3[i] + wc2 * C);
            float H = O * tanhf(C);
            outH[base + j] = H;
            outC[base + j] = C;
            // head: h[n,t] = bl[t] + sum_k relu(H_k) * Wl[k*HOR+t]
            float ah = blv;
            #pragma unroll 8
            for (int k = 0; k < HID; ++k) {
                float hv = __shfl(H, k, 32);
                if (j < HOR) ah += fmaxf(hv, 0.0f) * Wl[k * HOR + j];
            }
            if (j < HOR) hOut[n * HOR + j] = ah;
        }
        return;
    }

    // ---- general path ----
    float xk[NPT], lxk[NPT], hk[NPT], lhk[NPT];
    #pragma unroll
    for (int i = 0; i < NPT; ++i) { xk[i] = 0.0f; lxk[i] = 0.0f; hk[i] = 0.0f; lhk[i] = 0.0f; }
    for (int i = 0; i < cnt; ++i) {
        int n = n0 + i;
        int base = n << 5;
        xk[i] = X[base + j];
        hk[i] = H0[base + j];
        int beg = rowptr[n], end = rowptr[n + 1];
        float a = 0.0f, ah = 0.0f;
        if (f2 & 1) {
            #pragma unroll 4
            for (int e = beg; e < end; ++e) {
                int2 p = epair[e];
                float w = __int_as_float(p.y);
                a  += w * X[(p.x << 5) + j];
                ah += w * H0[(p.x << 5) + j];
            }
        } else {
            #pragma unroll 4
            for (int e = beg; e < end; ++e) {
                int2 p = epair[e];
                a += __int_as_float(p.y) * X[(p.x << 5) + j];
            }
        }
        lxk[i] = a;
        lhk[i] = ah;
    }

    float pre[4][NPT];
    #pragma unroll
    for (int gt = 0; gt < 4; ++gt) {
        float bb = bx[gt * HID + j] + bh[gt * HID + j] + b[gt * HID + j];
        #pragma unroll
        for (int i = 0; i < NPT; ++i) pre[gt][i] = bb;
    }

    #pragma unroll 2
    for (int k = 0; k < HID; ++k) {
        float w0[4], w1[4], w2[4], w3[4];
        int row = k * HID + j;
        #pragma unroll
        for (int gt = 0; gt < 4; ++gt) {
            w0[gt] = Wx[gt * 2048 + row];
            w1[gt] = Wx[gt * 2048 + 1024 + row];
            w2[gt] = Wh[gt * 2048 + row];
            w3[gt] = Wh[gt * 2048 + 1024 + row];
        }
        #pragma unroll
        for (int i = 0; i < NPT; ++i) {
            float xv  = __shfl(xk[i],  k, 32);
            float lxv = __shfl(lxk[i], k, 32);
            float hv  = __shfl(hk[i],  k, 32);
            float lhv = __shfl(lhk[i], k, 32);
            #pragma unroll
            for (int gt = 0; gt < 4; ++gt)
                pre[gt][i] += xv * w0[gt] + lxv * w1[gt] + hv * w2[gt] + lhv * w3[gt];
        }
    }

    float wc0 = wc[0 * HID + j], wc1 = wc[1 * HID + j], wc2 = wc[2 * HID + j];
    for (int i = 0; i < cnt; ++i) {
        int n = n0 + i;
        int base = n << 5;
        float c0v = C0[base + j];
        float I  = sigmoidf_(pre[0][i] + wc0 * c0v);
        float Fg = sigmoidf_(pre[1][i] + wc1 * c0v);
        float T  = tanhf(pre[2][i]);
        float C  = Fg * c0v + I * T;
        float O  = sigmoidf_(pre[3][i] + wc2 * C);
        float H  = O * tanhf(C);
        outH[base + j] = H;
        outC[base + j] = C;
        float ah = blv;
        #pragma unroll 8
        for (int k = 0; k < HID; ++k) {
            float hv = __shfl(H, k, 32);
            if (j < HOR) ah += fmaxf(hv, 0.0f) * Wl[k * HOR + j];
        }
        if (j < HOR) hOut[n * HOR + j] = ah;
    }
}

extern "C" void kernel_launch(void* const* d_in, const int* in_sizes, int n_in,
                              void* d_out, int out_size, void* d_ws, size_t ws_size,
                              hipStream_t stream) {
    const float* x  = (const float*)d_in[0];
    const int*   ei = (const int*)d_in[1];
    const float* ew = (const float*)d_in[2];
    const float* Wx = (const float*)d_in[3];
    const float* bx = (const float*)d_in[4];
    const float* Wh = (const float*)d_in[5];
    const float* bh = (const float*)d_in[6];
    const float* wc = (const float*)d_in[7];
    const float* b  = (const float*)d_in[8];
    const float* Wl = (const float*)d_in[9];
    const float* bl = (const float*)d_in[10];
    const float* h0 = (const float*)d_in[11];
    const float* c0 = (const float*)d_in[12];

    int N = in_sizes[0] / HID;      // x is (N,1,32)
    int E = in_sizes[2];            // edge_weight is (E,)
    const int* src = ei;
    const int* dst = ei + E;

    int ng = (N + GW - 1) >> GSH;   // 782 groups (requires N <= 65536)
    int ng2 = 2 * ng;
    int chunk = (E + NB - 1) / NB;  // edges per hist/scatter block

    // workspace (4-byte units):
    // [tmpD 2E] [tmpS 2E (aliased by epair)] [rowptr N+1]
    // [hist ng2*NB] [off ng2*NB] [binTot 2048] [baseS ng+1] [baseD ng+1] [dinv N] [flag 1]
    // tmpS is dead after k_degsum, so k_scatter2 may overwrite it with epair.
    int* wsi = (int*)d_ws;
    int2*  tmpD   = (int2*)wsi;
    int2*  tmpS   = (int2*)(wsi + 2 * (size_t)E);
    int2*  epair  = tmpS;                                // alias (see above)
    int*   rowptr = wsi + 4 * (size_t)E;
    int*   hist   = rowptr + (N + 1);
    int*   off    = hist + (size_t)ng2 * NB;
    int*   binTot = off + (size_t)ng2 * NB;
    int*   baseS  = binTot + 2048;
    int*   baseD  = baseS + (ng + 1);
    float* dinv   = (float*)(baseD + (ng + 1));
    int*   flag   = (int*)(dinv + N);

    float* hOut = (float*)d_out;            // (N,12)
    float* HOut = hOut + (size_t)N * HOR;   // (N,32)
    float* COut = HOut + (size_t)N * HID;   // (N,32)

    hipMemsetAsync(flag, 0, sizeof(int), stream);

    k_hist<<<NB, 1024, 0, stream>>>(src, dst, hist, E, chunk, ng);
    k_binscan<<<ng2, 256, 0, stream>>>(hist, off, binTot, ng2);
    k_binbase<<<2, 1024, 0, stream>>>(binTot, baseS, baseD, rowptr, E, ng, N);
    k_scatter<<<NB, 1024, 0, stream>>>(src, dst, ew, off, baseS, baseD, tmpS, tmpD, E, chunk, ng);
    k_degsum<<<ng, 256, 0, stream>>>(tmpS, baseS, dinv, N);
    k_flags<<<(N * HID + 255) / 256, 256, 0, stream>>>(h0, c0, flag, N * HID);
    k_scatter2<<<ng, 256, 0, stream>>>(tmpD, baseD, dinv, rowptr, epair, N);

    int gThreads = ((N + NPT - 1) / NPT) * 32;
    k_fused<<<(gThreads + 255) / 256, 256, 0, stream>>>(rowptr, epair, x, h0, c0,
                                                        Wx, bx, Wh, bh, wc, b, Wl, bl, flag,
                                                        hOut, HOut, COut, N);
}

// Round 8
// 274.764 us; speedup vs baseline: 2.0349x; 1.1789x over previous
//
#include <hip/hip_runtime.h>
#include <math.h>

#define HID 32
#define HOR 12
#define NB  256   // first-level blocks; k_binscan's 256 threads own one block each
#define GSH 8     // group shift: 256 nodes per group (392 write streams in scatter)
#define GW  256   // group width
#define NPT 4     // nodes per thread in k_gates

__device__ __forceinline__ float sigmoidf_(float x) { return 1.0f / (1.0f + expf(-x)); }

// ---------------------------------------------------------------------------
// Bucket sort by node id at 256-node granularity (node < 65536 required).
// Round-5 champion structure; GSH=8 shrinks scatter's open write-stream set
// (2*196 streams/block -> ~800KB partial lines per XCD L2, fits) to kill the
// 3.3x partial-line write amplification measured at GSH=6. k_head is fused
// into k_gates (H stays in registers). k_gather stays the latency-tolerant
// per-node form.
// ---------------------------------------------------------------------------

__global__ __launch_bounds__(1024) void k_hist(const int* __restrict__ src,
                                               const int* __restrict__ dst,
                                               int* __restrict__ hist,
                                               int E, int chunk, int ng) {
    __shared__ int hS[GW], hD[GW];
    int t = threadIdx.x, b = blockIdx.x;
    for (int i = t; i < ng; i += 1024) { hS[i] = 0; hD[i] = 0; }
    __syncthreads();
    int beg = b * chunk, end = min(E, beg + chunk);
    for (int e = beg + t; e < end; e += 1024) {
        atomicAdd(&hS[src[e] >> GSH], 1);
        atomicAdd(&hD[dst[e] >> GSH], 1);
    }
    __syncthreads();
    for (int i = t; i < ng; i += 1024) {
        hist[(size_t)i * NB + b] = hS[i];               // S bins: [0, ng)
        hist[((size_t)ng + i) * NB + b] = hD[i];        // D bins: [ng, 2ng)
    }
}

// per-bin exclusive scan across the NB blocks (one block per bin)
__global__ __launch_bounds__(256) void k_binscan(const int* __restrict__ hist,
                                                 int* __restrict__ off,
                                                 int* __restrict__ binTot, int ng2) {
    __shared__ int s[256];
    int b2 = blockIdx.x, t = threadIdx.x;
    int v = hist[(size_t)b2 * NB + t];                  // coalesced
    s[t] = v;
    __syncthreads();
    for (int o = 1; o < 256; o <<= 1) {
        int x = (t >= o) ? s[t - o] : 0;
        __syncthreads();
        s[t] += x;
        __syncthreads();
    }
    off[(size_t)t * ng2 + b2] = s[t] - v;               // block-major (scattered)
    if (t == 255) binTot[b2] = s[255];
}

// 2 blocks x 1024: block 0 scans S bin totals, block 1 scans D bin totals.
__global__ __launch_bounds__(1024) void k_binbase(const int* __restrict__ binTot,
                                                  int* __restrict__ baseS, int* __restrict__ baseD,
                                                  int* __restrict__ rowptr,
                                                  int E, int ng, int N) {
    __shared__ int buf[1024];
    int t = threadIdx.x;
    int isD = blockIdx.x;
    int sum = (t < ng) ? binTot[isD * ng + t] : 0;
    buf[t] = sum;
    __syncthreads();
    for (int o = 1; o < 1024; o <<= 1) {
        int v = (t >= o) ? buf[t - o] : 0;
        __syncthreads();
        buf[t] += v;
        __syncthreads();
    }
    int base = buf[t] - sum;                            // exclusive
    int* B = isD ? baseD : baseS;
    if (t < ng) B[t] = base;
    if (t == 0) { B[ng] = E; if (!isD) rowptr[N] = E; }
}

// per-edge scatter into 256-wide groups (both keyings) using LDS cursors.
__global__ __launch_bounds__(1024) void k_scatter(const int* __restrict__ src,
                                                  const int* __restrict__ dst,
                                                  const float* __restrict__ w,
                                                  const int* __restrict__ off,
                                                  const int* __restrict__ baseS,
                                                  const int* __restrict__ baseD,
                                                  int2* __restrict__ tmpS, int2* __restrict__ tmpD,
                                                  int E, int chunk, int ng) {
    __shared__ int cS[GW], cD[GW];
    int t = threadIdx.x, b = blockIdx.x;
    int ng2 = 2 * ng;
    for (int i = t; i < ng; i += 1024) {
        cS[i] = off[(size_t)b * ng2 + i] + baseS[i];          // coalesced
        cD[i] = off[(size_t)b * ng2 + ng + i] + baseD[i];
    }
    __syncthreads();
    int beg = b * chunk, end = min(E, beg + chunk);
    for (int e = beg + t; e < end; e += 1024) {
        int s = src[e], d = dst[e];
        int wb = __float_as_int(w[e]);
        int pS = atomicAdd(&cS[s >> GSH], 1);
        tmpS[pS] = make_int2(s, wb);
        int pD = atomicAdd(&cD[d >> GSH], 1);
        tmpD[pD] = make_int2(s | ((d & (GW - 1)) << 16), wb); // src fits 16 bits
    }
}

// per src-group: LDS float histogram over low 8 bits -> dinv (no global atomics)
__global__ __launch_bounds__(256) void k_degsum(const int2* __restrict__ tmpS,
                                                const int* __restrict__ baseS,
                                                float* __restrict__ dinv, int N) {
    __shared__ float h[GW];
    int g = blockIdx.x, t = threadIdx.x;
    h[t] = 0.0f;
    __syncthreads();
    int beg = baseS[g], end = baseS[g + 1];
    for (int i = beg + t; i < end; i += 256) {
        int2 p = tmpS[i];
        atomicAdd(&h[p.x & (GW - 1)], __int_as_float(p.y));
    }
    __syncthreads();
    int n = (g << GSH) + t;
    if (n < N) { float s = h[t]; dinv[n] = (s > 0.0f) ? rsqrtf(s) : 0.0f; }
}

// per dst-group: low-bits count + scan -> rowptr; then bin edges to exact dst,
// computing nw now that dinv exists. Within-dst order is arbitrary (sum).
__global__ __launch_bounds__(256) void k_scatter2(const int2* __restrict__ tmpD,
                                                  const int* __restrict__ baseD,
                                                  const float* __restrict__ dinv,
                                                  int* __restrict__ rowptr,
                                                  int2* __restrict__ epair, int N) {
    __shared__ int h[GW], cur[GW];
    int g = blockIdx.x, t = threadIdx.x;
    h[t] = 0;
    __syncthreads();
    int beg = baseD[g], end = baseD[g + 1];
    for (int i = beg + t; i < end; i += 256) atomicAdd(&h[(tmpD[i].x >> 16) & (GW - 1)], 1);
    __syncthreads();
    int v = h[t];
    for (int o = 1; o < GW; o <<= 1) {
        int x = (t >= o) ? h[t - o] : 0;
        __syncthreads();
        h[t] += x;
        __syncthreads();
    }
    int excl = h[t] - v;
    int n = (g << GSH) + t;
    if (n < N) rowptr[n] = beg + excl;
    cur[t] = beg + excl;
    __syncthreads();
    for (int i = beg + t; i < end; i += 256) {
        int2 p = tmpD[i];
        int low = (p.x >> 16) & (GW - 1);
        int s = p.x & 0xFFFF;
        int pos = atomicAdd(&cur[low], 1);
        float nw = -dinv[s] * __int_as_float(p.y) * dinv[(g << GSH) + low];
        epair[pos] = make_int2(s, __float_as_int(nw));
    }
}

// flag bit0 = any h0 nonzero, bit1 = any c0 nonzero
__global__ void k_flags(const float* __restrict__ h0, const float* __restrict__ c0,
                        int* __restrict__ flag, int total) {
    int i = blockIdx.x * 256 + threadIdx.x;
    float a = (i < total) ? h0[i] : 0.0f;
    float c = (i < total) ? c0[i] : 0.0f;
    unsigned long long ba = __ballot(a != 0.0f);
    unsigned long long bc = __ballot(c != 0.0f);
    if ((threadIdx.x & 63) == 0) {
        int m = (ba ? 1 : 0) | (bc ? 2 : 0);
        if (m) atomicOr(flag, m);
    }
}

// per dst node (32 lanes = 32 feats): accumulate LX (and LH if h0 nonzero)
__global__ __launch_bounds__(256) void k_gather(const int* __restrict__ rowptr,
                                                const int2* __restrict__ epair,
                                                const float* __restrict__ X,
                                                const float* __restrict__ H0,
                                                const int* __restrict__ hflag,
                                                float* __restrict__ LX, float* __restrict__ LH,
                                                int N) {
    int tid = blockIdx.x * 256 + threadIdx.x;
    int n = tid >> 5;
    int f = tid & 31;
    if (n >= N) return;
    int beg = rowptr[n], end = rowptr[n + 1];
    float acc = 0.0f, accH = 0.0f;
    int fl = *hflag;
    if (fl & 1) {
        #pragma unroll 4
        for (int i = beg; i < end; ++i) {
            int2 p = epair[i];
            float w = __int_as_float(p.y);
            acc  += w * X[(p.x << 5) + f];
            accH += w * H0[(p.x << 5) + f];
        }
    } else {
        #pragma unroll 4
        for (int i = beg; i < end; ++i) {
            int2 p = epair[i];
            acc += __int_as_float(p.y) * X[(p.x << 5) + f];
        }
    }
    LX[(n << 5) + f] = acc;
    if (fl & 1) LH[(n << 5) + f] = accH;   // LH is logically 0 otherwise; never read then
}

// Per (node-group g of NPT nodes, out-feature j): fused LSTM cell + head.
// Fast path (h0==0 && c0==0, detected at runtime): F-gate dead (C = I*T),
// h/lh terms are exact zero-adds -> 3 gates x 2 input types. Bit-identical.
// Head is computed inline from the register H via __shfl (no HOut re-read).
__global__ __launch_bounds__(256) void k_gates(
    const float* __restrict__ X, const float* __restrict__ LX,
    const float* __restrict__ H0, const float* __restrict__ LH,
    const float* __restrict__ C0,
    const float* __restrict__ Wx, const float* __restrict__ bx,
    const float* __restrict__ Wh, const float* __restrict__ bh,
    const float* __restrict__ wc, const float* __restrict__ b,
    const float* __restrict__ Wl, const float* __restrict__ bl,
    const int* __restrict__ flag,
    float* __restrict__ hOut, float* __restrict__ outH, float* __restrict__ outC,
    int N) {
    int tid = blockIdx.x * 256 + threadIdx.x;
    int g = tid >> 5;           // node group
    int j = tid & 31;           // output feature
    int n0 = g * NPT;
    if (n0 >= N) return;
    int cnt = min(NPT, N - n0);
    int f2 = *flag;
    float blv = (j < HOR) ? bl[j] : 0.0f;

    if (f2 == 0) {
        // ---- fast path: h0 == 0 and c0 == 0 ----
        float xk[NPT], lxk[NPT];
        #pragma unroll
        for (int i = 0; i < NPT; ++i) { xk[i] = 0.0f; lxk[i] = 0.0f; }
        for (int i = 0; i < cnt; ++i) {
            int base = (n0 + i) << 5;
            xk[i]  = X[base + j];
            lxk[i] = LX[base + j];
        }
        float p0[NPT], p2[NPT], p3[NPT];
        float b0 = bx[0 * HID + j] + bh[0 * HID + j] + b[0 * HID + j];
        float b2 = bx[2 * HID + j] + bh[2 * HID + j] + b[2 * HID + j];
        float b3 = bx[3 * HID + j] + bh[3 * HID + j] + b[3 * HID + j];
        #pragma unroll
        for (int i = 0; i < NPT; ++i) { p0[i] = b0; p2[i] = b2; p3[i] = b3; }

        #pragma unroll 4
        for (int k = 0; k < HID; ++k) {
            int row = k * HID + j;
            float w00 = Wx[0 * 2048 + row], w01 = Wx[0 * 2048 + 1024 + row];
            float w20 = Wx[2 * 2048 + row], w21 = Wx[2 * 2048 + 1024 + row];
            float w30 = Wx[3 * 2048 + row], w31 = Wx[3 * 2048 + 1024 + row];
            #pragma unroll
            for (int i = 0; i < NPT; ++i) {
                float xv  = __shfl(xk[i],  k, 32);
                float lxv = __shfl(lxk[i], k, 32);
                p0[i] += xv * w00 + lxv * w01;
                p2[i] += xv * w20 + lxv * w21;
                p3[i] += xv * w30 + lxv * w31;
            }
        }

        float wc2 = wc[2 * HID + j];
        for (int i = 0; i < cnt; ++i) {
            int n = n0 + i;
            int base = n << 5;
            float I = sigmoidf_(p0[i]);
            float T = tanhf(p2[i]);
            float C = I * T;
            float O = sigmoidf_(p3[i] + wc2 * C);
            float H = O * tanhf(C);
            outH[base + j] = H;
            outC[base + j] = C;
            float ah = blv;
            #pragma unroll 8
            for (int k = 0; k < HID; ++k) {
                float hv = __shfl(H, k, 32);
                if (j < HOR) ah += fmaxf(hv, 0.0f) * Wl[k * HOR + j];
            }
            if (j < HOR) hOut[n * HOR + j] = ah;
        }
        return;
    }

    // ---- general path ----
    float xk[NPT], lxk[NPT], hk[NPT], lhk[NPT];
    #pragma unroll
    for (int i = 0; i < NPT; ++i) { xk[i] = 0.0f; lxk[i] = 0.0f; hk[i] = 0.0f; lhk[i] = 0.0f; }
    for (int i = 0; i < cnt; ++i) {
        int base = (n0 + i) << 5;
        xk[i]  = X[base + j];
        lxk[i] = LX[base + j];
        hk[i]  = H0[base + j];
        lhk[i] = (f2 & 1) ? LH[base + j] : 0.0f;   // LH only valid if h0 nonzero
    }

    float pre[4][NPT];
    #pragma unroll
    for (int gt = 0; gt < 4; ++gt) {
        float bb = bx[gt * HID + j] + bh[gt * HID + j] + b[gt * HID + j];
        #pragma unroll
        for (int i = 0; i < NPT; ++i) pre[gt][i] = bb;
    }

    #pragma unroll 2
    for (int k = 0; k < HID; ++k) {
        float w0[4], w1[4], w2[4], w3[4];
        int row = k * HID + j;
        #pragma unroll
        for (int gt = 0; gt < 4; ++gt) {
            w0[gt] = Wx[gt * 2048 + row];
            w1[gt] = Wx[gt * 2048 + 1024 + row];
            w2[gt] = Wh[gt * 2048 + row];
            w3[gt] = Wh[gt * 2048 + 1024 + row];
        }
        #pragma unroll
        for (int i = 0; i < NPT; ++i) {
            float xv  = __shfl(xk[i],  k, 32);
            float lxv = __shfl(lxk[i], k, 32);
            float hv  = __shfl(hk[i],  k, 32);
            float lhv = __shfl(lhk[i], k, 32);
            #pragma unroll
            for (int gt = 0; gt < 4; ++gt)
                pre[gt][i] += xv * w0[gt] + lxv * w1[gt] + hv * w2[gt] + lhv * w3[gt];
        }
    }

    float wc0 = wc[0 * HID + j], wc1 = wc[1 * HID + j], wc2 = wc[2 * HID + j];
    for (int i = 0; i < cnt; ++i) {
        int n = n0 + i;
        int base = n << 5;
        float c0v = C0[base + j];
        float I  = sigmoidf_(pre[0][i] + wc0 * c0v);
        float Fg = sigmoidf_(pre[1][i] + wc1 * c0v);
        float T  = tanhf(pre[2][i]);
        float C  = Fg * c0v + I * T;
        float O  = sigmoidf_(pre[3][i] + wc2 * C);
        float H  = O * tanhf(C);
        outH[base + j] = H;
        outC[base + j] = C;
        float ah = blv;
        #pragma unroll 8
        for (int k = 0; k < HID; ++k) {
            float hv = __shfl(H, k, 32);
            if (j < HOR) ah += fmaxf(hv, 0.0f) * Wl[k * HOR + j];
        }
        if (j < HOR) hOut[n * HOR + j] = ah;
    }
}

extern "C" void kernel_launch(void* const* d_in, const int* in_sizes, int n_in,
                              void* d_out, int out_size, void* d_ws, size_t ws_size,
                              hipStream_t stream) {
    const float* x  = (const float*)d_in[0];
    const int*   ei = (const int*)d_in[1];
    const float* ew = (const float*)d_in[2];
    const float* Wx = (const float*)d_in[3];
    const float* bx = (const float*)d_in[4];
    const float* Wh = (const float*)d_in[5];
    const float* bh = (const float*)d_in[6];
    const float* wc = (const float*)d_in[7];
    const float* b  = (const float*)d_in[8];
    const float* Wl = (const float*)d_in[9];
    const float* bl = (const float*)d_in[10];
    const float* h0 = (const float*)d_in[11];
    const float* c0 = (const float*)d_in[12];

    int N = in_sizes[0] / HID;      // x is (N,1,32)
    int E = in_sizes[2];            // edge_weight is (E,)
    const int* src = ei;
    const int* dst = ei + E;

    int ng = (N + GW - 1) >> GSH;   // 196 groups (requires N <= 65536)
    int ng2 = 2 * ng;
    int chunk = (E + NB - 1) / NB;  // edges per hist/scatter block

    // workspace (4-byte units):
    // [tmpD 2E] [tmpS 2E (aliased by epair)] [LX N*32] [LH N*32] [rowptr N+1]
    // [hist ng2*NB] [off ng2*NB] [binTot 2048] [baseS ng+1] [baseD ng+1] [dinv N] [flag 1]
    // tmpS is dead after k_degsum, so k_scatter2 may overwrite it with epair.
    int* wsi = (int*)d_ws;
    int2*  tmpD   = (int2*)wsi;
    int2*  tmpS   = (int2*)(wsi + 2 * (size_t)E);
    int2*  epair  = tmpS;                                // alias (see above)
    float* LX     = (float*)(wsi + 4 * (size_t)E);
    float* LH     = LX + (size_t)N * HID;
    int*   rowptr = (int*)(LH + (size_t)N * HID);
    int*   hist   = rowptr + (N + 1);
    int*   off    = hist + (size_t)ng2 * NB;
    int*   binTot = off + (size_t)ng2 * NB;
    int*   baseS  = binTot + 2048;
    int*   baseD  = baseS + (ng + 1);
    float* dinv   = (float*)(baseD + (ng + 1));
    int*   flag   = (int*)(dinv + N);

    float* hOut = (float*)d_out;            // (N,12)
    float* HOut = hOut + (size_t)N * HOR;   // (N,32)
    float* COut = HOut + (size_t)N * HID;   // (N,32)

    hipMemsetAsync(flag, 0, sizeof(int), stream);

    k_hist<<<NB, 1024, 0, stream>>>(src, dst, hist, E, chunk, ng);
    k_binscan<<<ng2, 256, 0, stream>>>(hist, off, binTot, ng2);
    k_binbase<<<2, 1024, 0, stream>>>(binTot, baseS, baseD, rowptr, E, ng, N);
    k_scatter<<<NB, 1024, 0, stream>>>(src, dst, ew, off, baseS, baseD, tmpS, tmpD, E, chunk, ng);
    k_degsum<<<ng, 256, 0, stream>>>(tmpS, baseS, dinv, N);
    k_flags<<<(N * HID + 255) / 256, 256, 0, stream>>>(h0, c0, flag, N * HID);
    k_scatter2<<<ng, 256, 0, stream>>>(tmpD, baseD, dinv, rowptr, epair, N);

    k_gather<<<(N * HID + 255) / 256, 256, 0, stream>>>(rowptr, epair, x, h0, flag, LX, LH, N);

    int gThreads = ((N + NPT - 1) / NPT) * 32;
    k_gates<<<(gThreads + 255) / 256, 256, 0, stream>>>(x, LX, h0, LH, c0,
                                                        Wx, bx, Wh, bh, wc, b, Wl, bl, flag,
                                                        hOut, HOut, COut, N);
}

// Round 9
// 272.346 us; speedup vs baseline: 2.0530x; 1.0089x over previous
//
#include <hip/hip_runtime.h>
#include <math.h>

#define HID 32
#define HOR 12
#define NB  256   // first-level blocks; k_binscan's 256 threads own one block each
#define GSH 8     // group shift: 256 nodes per group (392 write streams in scatter)
#define GW  256   // group width
#define NPT 4     // nodes per thread in k_gates

__device__ __forceinline__ float sigmoidf_(float x) { return 1.0f / (1.0f + expf(-x)); }

// ---------------------------------------------------------------------------
// Pipeline identical to round 8 except k_gates: the fast path's shfl-based
// input broadcast (256 ds_bpermute/wave) and head (128 shfl/wave) are replaced
// by LDS staging + wave-uniform ds_read_b128 broadcasts (64+36 DS ops/wave,
// each feeding 4x the FMAs). Staging is wave-local; barriers kept for safety.
// ---------------------------------------------------------------------------

__global__ __launch_bounds__(1024) void k_hist(const int* __restrict__ src,
                                               const int* __restrict__ dst,
                                               int* __restrict__ hist,
                                               int E, int chunk, int ng) {
    __shared__ int hS[GW], hD[GW];
    int t = threadIdx.x, b = blockIdx.x;
    for (int i = t; i < ng; i += 1024) { hS[i] = 0; hD[i] = 0; }
    __syncthreads();
    int beg = b * chunk, end = min(E, beg + chunk);
    for (int e = beg + t; e < end; e += 1024) {
        atomicAdd(&hS[src[e] >> GSH], 1);
        atomicAdd(&hD[dst[e] >> GSH], 1);
    }
    __syncthreads();
    for (int i = t; i < ng; i += 1024) {
        hist[(size_t)i * NB + b] = hS[i];               // S bins: [0, ng)
        hist[((size_t)ng + i) * NB + b] = hD[i];        // D bins: [ng, 2ng)
    }
}

// per-bin exclusive scan across the NB blocks (one block per bin)
__global__ __launch_bounds__(256) void k_binscan(const int* __restrict__ hist,
                                                 int* __restrict__ off,
                                                 int* __restrict__ binTot, int ng2) {
    __shared__ int s[256];
    int b2 = blockIdx.x, t = threadIdx.x;
    int v = hist[(size_t)b2 * NB + t];                  // coalesced
    s[t] = v;
    __syncthreads();
    for (int o = 1; o < 256; o <<= 1) {
        int x = (t >= o) ? s[t - o] : 0;
        __syncthreads();
        s[t] += x;
        __syncthreads();
    }
    off[(size_t)t * ng2 + b2] = s[t] - v;               // block-major (scattered)
    if (t == 255) binTot[b2] = s[255];
}

// 2 blocks x 1024: block 0 scans S bin totals, block 1 scans D bin totals.
__global__ __launch_bounds__(1024) void k_binbase(const int* __restrict__ binTot,
                                                  int* __restrict__ baseS, int* __restrict__ baseD,
                                                  int* __restrict__ rowptr,
                                                  int E, int ng, int N) {
    __shared__ int buf[1024];
    int t = threadIdx.x;
    int isD = blockIdx.x;
    int sum = (t < ng) ? binTot[isD * ng + t] : 0;
    buf[t] = sum;
    __syncthreads();
    for (int o = 1; o < 1024; o <<= 1) {
        int v = (t >= o) ? buf[t - o] : 0;
        __syncthreads();
        buf[t] += v;
        __syncthreads();
    }
    int base = buf[t] - sum;                            // exclusive
    int* B = isD ? baseD : baseS;
    if (t < ng) B[t] = base;
    if (t == 0) { B[ng] = E; if (!isD) rowptr[N] = E; }
}

// per-edge scatter into 256-wide groups (both keyings) using LDS cursors.
__global__ __launch_bounds__(1024) void k_scatter(const int* __restrict__ src,
                                                  const int* __restrict__ dst,
                                                  const float* __restrict__ w,
                                                  const int* __restrict__ off,
                                                  const int* __restrict__ baseS,
                                                  const int* __restrict__ baseD,
                                                  int2* __restrict__ tmpS, int2* __restrict__ tmpD,
                                                  int E, int chunk, int ng) {
    __shared__ int cS[GW], cD[GW];
    int t = threadIdx.x, b = blockIdx.x;
    int ng2 = 2 * ng;
    for (int i = t; i < ng; i += 1024) {
        cS[i] = off[(size_t)b * ng2 + i] + baseS[i];          // coalesced
        cD[i] = off[(size_t)b * ng2 + ng + i] + baseD[i];
    }
    __syncthreads();
    int beg = b * chunk, end = min(E, beg + chunk);
    for (int e = beg + t; e < end; e += 1024) {
        int s = src[e], d = dst[e];
        int wb = __float_as_int(w[e]);
        int pS = atomicAdd(&cS[s >> GSH], 1);
        tmpS[pS] = make_int2(s, wb);
        int pD = atomicAdd(&cD[d >> GSH], 1);
        tmpD[pD] = make_int2(s | ((d & (GW - 1)) << 16), wb); // src fits 16 bits
    }
}

// per src-group: LDS float histogram over low 8 bits -> dinv (no global atomics)
__global__ __launch_bounds__(256) void k_degsum(const int2* __restrict__ tmpS,
                                                const int* __restrict__ baseS,
                                                float* __restrict__ dinv, int N) {
    __shared__ float h[GW];
    int g = blockIdx.x, t = threadIdx.x;
    h[t] = 0.0f;
    __syncthreads();
    int beg = baseS[g], end = baseS[g + 1];
    for (int i = beg + t; i < end; i += 256) {
        int2 p = tmpS[i];
        atomicAdd(&h[p.x & (GW - 1)], __int_as_float(p.y));
    }
    __syncthreads();
    int n = (g << GSH) + t;
    if (n < N) { float s = h[t]; dinv[n] = (s > 0.0f) ? rsqrtf(s) : 0.0f; }
}

// per dst-group: low-bits count + scan -> rowptr; then bin edges to exact dst,
// computing nw now that dinv exists. Within-dst order is arbitrary (sum).
__global__ __launch_bounds__(256) void k_scatter2(const int2* __restrict__ tmpD,
                                                  const int* __restrict__ baseD,
                                                  const float* __restrict__ dinv,
                                                  int* __restrict__ rowptr,
                                                  int2* __restrict__ epair, int N) {
    __shared__ int h[GW], cur[GW];
    int g = blockIdx.x, t = threadIdx.x;
    h[t] = 0;
    __syncthreads();
    int beg = baseD[g], end = baseD[g + 1];
    for (int i = beg + t; i < end; i += 256) atomicAdd(&h[(tmpD[i].x >> 16) & (GW - 1)], 1);
    __syncthreads();
    int v = h[t];
    for (int o = 1; o < GW; o <<= 1) {
        int x = (t >= o) ? h[t - o] : 0;
        __syncthreads();
        h[t] += x;
        __syncthreads();
    }
    int excl = h[t] - v;
    int n = (g << GSH) + t;
    if (n < N) rowptr[n] = beg + excl;
    cur[t] = beg + excl;
    __syncthreads();
    for (int i = beg + t; i < end; i += 256) {
        int2 p = tmpD[i];
        int low = (p.x >> 16) & (GW - 1);
        int s = p.x & 0xFFFF;
        int pos = atomicAdd(&cur[low], 1);
        float nw = -dinv[s] * __int_as_float(p.y) * dinv[(g << GSH) + low];
        epair[pos] = make_int2(s, __float_as_int(nw));
    }
}

// flag bit0 = any h0 nonzero, bit1 = any c0 nonzero
__global__ void k_flags(const float* __restrict__ h0, const float* __restrict__ c0,
                        int* __restrict__ flag, int total) {
    int i = blockIdx.x * 256 + threadIdx.x;
    float a = (i < total) ? h0[i] : 0.0f;
    float c = (i < total) ? c0[i] : 0.0f;
    unsigned long long ba = __ballot(a != 0.0f);
    unsigned long long bc = __ballot(c != 0.0f);
    if ((threadIdx.x & 63) == 0) {
        int m = (ba ? 1 : 0) | (bc ? 2 : 0);
        if (m) atomicOr(flag, m);
    }
}

// per dst node (32 lanes = 32 feats): accumulate LX (and LH if h0 nonzero)
__global__ __launch_bounds__(256) void k_gather(const int* __restrict__ rowptr,
                                                const int2* __restrict__ epair,
                                                const float* __restrict__ X,
                                                const float* __restrict__ H0,
                                                const int* __restrict__ hflag,
                                                float* __restrict__ LX, float* __restrict__ LH,
                                                int N) {
    int tid = blockIdx.x * 256 + threadIdx.x;
    int n = tid >> 5;
    int f = tid & 31;
    if (n >= N) return;
    int beg = rowptr[n], end = rowptr[n + 1];
    float acc = 0.0f, accH = 0.0f;
    int fl = *hflag;
    if (fl & 1) {
        #pragma unroll 4
        for (int i = beg; i < end; ++i) {
            int2 p = epair[i];
            float w = __int_as_float(p.y);
            acc  += w * X[(p.x << 5) + f];
            accH += w * H0[(p.x << 5) + f];
        }
    } else {
        #pragma unroll 4
        for (int i = beg; i < end; ++i) {
            int2 p = epair[i];
            acc += __int_as_float(p.y) * X[(p.x << 5) + f];
        }
    }
    LX[(n << 5) + f] = acc;
    if (fl & 1) LH[(n << 5) + f] = accH;   // LH is logically 0 otherwise; never read then
}

// Per (node-group g of NPT nodes, out-feature j): fused LSTM cell + head.
// Fast path: inputs broadcast via LDS ds_read_b128 (no shuffles); head via a
// 4KB LDS H tile. General path keeps the proven shfl form (correctness-only).
__global__ __launch_bounds__(256) void k_gates(
    const float* __restrict__ X, const float* __restrict__ LX,
    const float* __restrict__ H0, const float* __restrict__ LH,
    const float* __restrict__ C0,
    const float* __restrict__ Wx, const float* __restrict__ bx,
    const float* __restrict__ Wh, const float* __restrict__ bh,
    const float* __restrict__ wc, const float* __restrict__ b,
    const float* __restrict__ Wl, const float* __restrict__ bl,
    const int* __restrict__ flag,
    float* __restrict__ hOut, float* __restrict__ outH, float* __restrict__ outC,
    int N) {
    __shared__ float X_lds[32 * HID];    // 32 nodes per block
    __shared__ float LX_lds[32 * HID];
    __shared__ float H_lds[32 * HID];

    int tid = blockIdx.x * 256 + threadIdx.x;
    int gl = threadIdx.x >> 5;   // block-local group 0..7
    int g = tid >> 5;            // global node group
    int j = tid & 31;            // output feature
    int n0 = g * NPT;
    int f2 = *flag;
    float blv = (j < HOR) ? bl[j] : 0.0f;

    if (f2 == 0) {
        // ---- fast path: h0 == 0 and c0 == 0 ----
        // wave-local staging of this wave's 8 nodes (rows wv*8 .. wv*8+7)
        int wv = threadIdx.x >> 6;             // wave in block 0..3
        int lane = threadIdx.x & 63;
        int wNode0 = blockIdx.x * 32 + wv * 8;
        if (wNode0 + 8 <= N) {
            const float4* Xs = (const float4*)(X + ((size_t)wNode0 << 5));
            const float4* Ls = (const float4*)(LX + ((size_t)wNode0 << 5));
            float4 xa = Xs[lane];
            float4 la = Ls[lane];
            *((float4*)&X_lds[(wv * 8) << 5] + lane) = xa;
            *((float4*)&LX_lds[(wv * 8) << 5] + lane) = la;
        } else {
            for (int q = lane; q < 256; q += 64) {
                int n = wNode0 + (q >> 5);
                X_lds[((wv * 8) << 5) + q]  = (n < N) ? X[((size_t)n << 5) + (q & 31)] : 0.0f;
                LX_lds[((wv * 8) << 5) + q] = (n < N) ? LX[((size_t)n << 5) + (q & 31)] : 0.0f;
            }
        }
        __syncthreads();

        float p0[NPT], p2[NPT], p3[NPT];
        float b0 = bx[0 * HID + j] + bh[0 * HID + j] + b[0 * HID + j];
        float b2 = bx[2 * HID + j] + bh[2 * HID + j] + b[2 * HID + j];
        float b3 = bx[3 * HID + j] + bh[3 * HID + j] + b[3 * HID + j];
        #pragma unroll
        for (int i = 0; i < NPT; ++i) { p0[i] = b0; p2[i] = b2; p3[i] = b3; }

        if (n0 < N) {
            #pragma unroll
            for (int kb = 0; kb < HID / 4; ++kb) {
                float4 xq[NPT], lq[NPT];
                #pragma unroll
                for (int i = 0; i < NPT; ++i) {
                    int row = ((gl * NPT + i) << 5) + kb * 4;
                    xq[i] = *(const float4*)&X_lds[row];    // wave-uniform addr: broadcast
                    lq[i] = *(const float4*)&LX_lds[row];
                }
                #pragma unroll
                for (int dk = 0; dk < 4; ++dk) {
                    int row = (kb * 4 + dk) * HID + j;
                    float w00 = Wx[row],            w01 = Wx[1024 + row];
                    float w20 = Wx[2 * 2048 + row], w21 = Wx[2 * 2048 + 1024 + row];
                    float w30 = Wx[3 * 2048 + row], w31 = Wx[3 * 2048 + 1024 + row];
                    #pragma unroll
                    for (int i = 0; i < NPT; ++i) {
                        float xv  = (dk == 0) ? xq[i].x : (dk == 1) ? xq[i].y : (dk == 2) ? xq[i].z : xq[i].w;
                        float lxv = (dk == 0) ? lq[i].x : (dk == 1) ? lq[i].y : (dk == 2) ? lq[i].z : lq[i].w;
                        p0[i] += xv * w00 + lxv * w01;
                        p2[i] += xv * w20 + lxv * w21;
                        p3[i] += xv * w30 + lxv * w31;
                    }
                }
            }

            float wc2 = wc[2 * HID + j];
            #pragma unroll
            for (int i = 0; i < NPT; ++i) {
                int n = n0 + i;
                if (n < N) {
                    int base = n << 5;
                    float I = sigmoidf_(p0[i]);
                    float T = tanhf(p2[i]);
                    float C = I * T;
                    float O = sigmoidf_(p3[i] + wc2 * C);
                    float H = O * tanhf(C);
                    outH[base + j] = H;
                    outC[base + j] = C;
                    H_lds[((gl * NPT + i) << 5) + j] = fmaxf(H, 0.0f);  // relu pre-applied
                }
            }
        }
        __syncthreads();

        // head from LDS: lanes j<12, wave-uniform b128 broadcasts per node
        if (n0 < N && j < HOR) {
            #pragma unroll
            for (int i = 0; i < NPT; ++i) {
                int n = n0 + i;
                if (n < N) {
                    float ah = blv;
                    #pragma unroll
                    for (int kb = 0; kb < HID / 4; ++kb) {
                        float4 hq = *(const float4*)&H_lds[((gl * NPT + i) << 5) + kb * 4];
                        ah += hq.x * Wl[(kb * 4 + 0) * HOR + j];
                        ah += hq.y * Wl[(kb * 4 + 1) * HOR + j];
                        ah += hq.z * Wl[(kb * 4 + 2) * HOR + j];
                        ah += hq.w * Wl[(kb * 4 + 3) * HOR + j];
                    }
                    hOut[(size_t)n * HOR + j] = ah;
                }
            }
        }
        return;
    }

    // ---- general path (shfl form; correctness-only) ----
    if (n0 >= N) return;
    int cnt = min(NPT, N - n0);
    float xk[NPT], lxk[NPT], hk[NPT], lhk[NPT];
    #pragma unroll
    for (int i = 0; i < NPT; ++i) { xk[i] = 0.0f; lxk[i] = 0.0f; hk[i] = 0.0f; lhk[i] = 0.0f; }
    for (int i = 0; i < cnt; ++i) {
        int base = (n0 + i) << 5;
        xk[i]  = X[base + j];
        lxk[i] = LX[base + j];
        hk[i]  = H0[base + j];
        lhk[i] = (f2 & 1) ? LH[base + j] : 0.0f;   // LH only valid if h0 nonzero
    }

    float pre[4][NPT];
    #pragma unroll
    for (int gt = 0; gt < 4; ++gt) {
        float bb = bx[gt * HID + j] + bh[gt * HID + j] + b[gt * HID + j];
        #pragma unroll
        for (int i = 0; i < NPT; ++i) pre[gt][i] = bb;
    }

    #pragma unroll 2
    for (int k = 0; k < HID; ++k) {
        float w0[4], w1[4], w2[4], w3[4];
        int row = k * HID + j;
        #pragma unroll
        for (int gt = 0; gt < 4; ++gt) {
            w0[gt] = Wx[gt * 2048 + row];
            w1[gt] = Wx[gt * 2048 + 1024 + row];
            w2[gt] = Wh[gt * 2048 + row];
            w3[gt] = Wh[gt * 2048 + 1024 + row];
        }
        #pragma unroll
        for (int i = 0; i < NPT; ++i) {
            float xv  = __shfl(xk[i],  k, 32);
            float lxv = __shfl(lxk[i], k, 32);
            float hv  = __shfl(hk[i],  k, 32);
            float lhv = __shfl(lhk[i], k, 32);
            #pragma unroll
            for (int gt = 0; gt < 4; ++gt)
                pre[gt][i] += xv * w0[gt] + lxv * w1[gt] + hv * w2[gt] + lhv * w3[gt];
        }
    }

    float wc0 = wc[0 * HID + j], wc1 = wc[1 * HID + j], wc2 = wc[2 * HID + j];
    for (int i = 0; i < cnt; ++i) {
        int n = n0 + i;
        int base = n << 5;
        float c0v = C0[base + j];
        float I  = sigmoidf_(pre[0][i] + wc0 * c0v);
        float Fg = sigmoidf_(pre[1][i] + wc1 * c0v);
        float T  = tanhf(pre[2][i]);
        float C  = Fg * c0v + I * T;
        float O  = sigmoidf_(pre[3][i] + wc2 * C);
        float H  = O * tanhf(C);
        outH[base + j] = H;
        outC[base + j] = C;
        float ah = blv;
        #pragma unroll 8
        for (int k = 0; k < HID; ++k) {
            float hv = __shfl(H, k, 32);
            if (j < HOR) ah += fmaxf(hv, 0.0f) * Wl[k * HOR + j];
        }
        if (j < HOR) hOut[(size_t)n * HOR + j] = ah;
    }
}

extern "C" void kernel_launch(void* const* d_in, const int* in_sizes, int n_in,
                              void* d_out, int out_size, void* d_ws, size_t ws_size,
                              hipStream_t stream) {
    const float* x  = (const float*)d_in[0];
    const int*   ei = (const int*)d_in[1];
    const float* ew = (const float*)d_in[2];
    const float* Wx = (const float*)d_in[3];
    const float* bx = (const float*)d_in[4];
    const float* Wh = (const float*)d_in[5];
    const float* bh = (const float*)d_in[6];
    const float* wc = (const float*)d_in[7];
    const float* b  = (const float*)d_in[8];
    const float* Wl = (const float*)d_in[9];
    const float* bl = (const float*)d_in[10];
    const float* h0 = (const float*)d_in[11];
    const float* c0 = (const float*)d_in[12];

    int N = in_sizes[0] / HID;      // x is (N,1,32)
    int E = in_sizes[2];            // edge_weight is (E,)
    const int* src = ei;
    const int* dst = ei + E;

    int ng = (N + GW - 1) >> GSH;   // 196 groups (requires N <= 65536)
    int ng2 = 2 * ng;
    int chunk = (E + NB - 1) / NB;  // edges per hist/scatter block

    // workspace (4-byte units):
    // [tmpD 2E] [tmpS 2E (aliased by epair)] [LX N*32] [LH N*32] [rowptr N+1]
    // [hist ng2*NB] [off ng2*NB] [binTot 2048] [baseS ng+1] [baseD ng+1] [dinv N] [flag 1]
    // tmpS is dead after k_degsum, so k_scatter2 may overwrite it with epair.
    int* wsi = (int*)d_ws;
    int2*  tmpD   = (int2*)wsi;
    int2*  tmpS   = (int2*)(wsi + 2 * (size_t)E);
    int2*  epair  = tmpS;                                // alias (see above)
    float* LX     = (float*)(wsi + 4 * (size_t)E);
    float* LH     = LX + (size_t)N * HID;
    int*   rowptr = (int*)(LH + (size_t)N * HID);
    int*   hist   = rowptr + (N + 1);
    int*   off    = hist + (size_t)ng2 * NB;
    int*   binTot = off + (size_t)ng2 * NB;
    int*   baseS  = binTot + 2048;
    int*   baseD  = baseS + (ng + 1);
    float* dinv   = (float*)(baseD + (ng + 1));
    int*   flag   = (int*)(dinv + N);

    float* hOut = (float*)d_out;            // (N,12)
    float* HOut = hOut + (size_t)N * HOR;   // (N,32)
    float* COut = HOut + (size_t)N * HID;   // (N,32)

    hipMemsetAsync(flag, 0, sizeof(int), stream);

    k_hist<<<NB, 1024, 0, stream>>>(src, dst, hist, E, chunk, ng);
    k_binscan<<<ng2, 256, 0, stream>>>(hist, off, binTot, ng2);
    k_binbase<<<2, 1024, 0, stream>>>(binTot, baseS, baseD, rowptr, E, ng, N);
    k_scatter<<<NB, 1024, 0, stream>>>(src, dst, ew, off, baseS, baseD, tmpS, tmpD, E, chunk, ng);
    k_degsum<<<ng, 256, 0, stream>>>(tmpS, baseS, dinv, N);
    k_flags<<<(N * HID + 255) / 256, 256, 0, stream>>>(h0, c0, flag, N * HID);
    k_scatter2<<<ng, 256, 0, stream>>>(tmpD, baseD, dinv, rowptr, epair, N);

    k_gather<<<(N * HID + 255) / 256, 256, 0, stream>>>(rowptr, epair, x, h0, flag, LX, LH, N);

    int gThreads = ((N + NPT - 1) / NPT) * 32;
    k_gates<<<(gThreads + 255) / 256, 256, 0, stream>>>(x, LX, h0, LH, c0,
                                                        Wx, bx, Wh, bh, wc, b, Wl, bl, flag,
                                                        hOut, HOut, COut, N);
}